// Round 5
// baseline (324.675 us; speedup 1.0000x reference)
//
#include <hip/hip_runtime.h>
#include <stdint.h>

// Problem constants (fixed by setup_inputs): B=8192, I=512, H=1024
#define BATCH 8192
#define IDIM  512
#define HDIM  1024
#define KDIM  1536          // I + H
#define NDIM  4096          // 4*H
#define NKT   (KDIM / 32)   // 48 k-tiles of 32

typedef __bf16 bf16x8 __attribute__((ext_vector_type(8)));
typedef float  f32x4  __attribute__((ext_vector_type(4)));
typedef unsigned short u16x8 __attribute__((ext_vector_type(8)));

__device__ __forceinline__ unsigned short f2bf(float f) {
    union { float f; unsigned u; } v; v.f = f;
    unsigned r = v.u + 0x7fffu + ((v.u >> 16) & 1u);   // RNE
    return (unsigned short)(r >> 16);
}
__device__ __forceinline__ float bf2f(unsigned short u) {
    union { unsigned u; float f; } v; v.u = ((unsigned)u) << 16;
    return v.f;
}
__device__ __forceinline__ float fexp(float x) {      // e^x via v_exp_f32
    return __builtin_amdgcn_exp2f(x * 1.44269504f);
}
__device__ __forceinline__ float sigm(float x) {      // stable for |x| large
    return __builtin_amdgcn_rcpf(1.f + fexp(-x));
}
__device__ __forceinline__ float ftanh(float x) {     // 1 - 2/(e^{2x}+1)
    return 1.f - 2.f * __builtin_amdgcn_rcpf(1.f + fexp(2.f * x));
}

// Fragment-layout address (in shorts) for element (row, k) of a row-major
// [R x KDIM] bf16 matrix packed for mfma_f32_16x16x32_bf16 A/B operands:
// 1024B block per (row16, kt) fragment; within: lane = (row&15) + 16*((k>>3)&3)
// holds 8 halfwords k = (k&~7)..(k|7). A wave's fragment load is then
// global_load_dwordx4 at block_base + lane*16B: perfectly coalesced 1024B.
__device__ __forceinline__ size_t frag_addr(int row, int k) {
    return ((size_t)((row >> 4) * NKT + (k >> 5)) << 9)
         + (((row & 15) + 16 * ((k >> 3) & 3)) << 3) + (k & 7);
}

// ------------- Kernel 1: fused input packing ------------------------------
// blocks [0, NPACKA): pack [x|h] -> bf16 A (BATCH x KDIM), FRAGMENT layout
// blocks [NPACKA, ..): transpose+convert [Wi;Wh] -> bf16 Wt (NDIM x KDIM),
//                      FRAGMENT layout
#define NPACKA (BATCH * KDIM / 4 / 256)      // 12288
#define NPACKW ((NDIM / 32) * (KDIM / 32))   // 6144
__global__ __launch_bounds__(256) void pack_ab(const float* __restrict__ x,
                                               const float* __restrict__ h,
                                               const float* __restrict__ Wi,
                                               const float* __restrict__ Wh,
                                               unsigned short* __restrict__ A,
                                               unsigned short* __restrict__ Wt) {
    __shared__ float tile[32][33];
    int blk = blockIdx.x;
    if (blk < NPACKA) {
        int idx = blk * 256 + threadIdx.x;   // group of 4 elements
        int row = idx / (KDIM / 4);
        int g   = idx % (KDIM / 4);
        int col = g * 4;
        float4 v;
        if (col < IDIM) v = ((const float4*)(x + (size_t)row * IDIM))[g];
        else            v = ((const float4*)(h + (size_t)row * HDIM))[(col - IDIM) / 4];
        ushort4 o;
        o.x = f2bf(v.x); o.y = f2bf(v.y); o.z = f2bf(v.z); o.w = f2bf(v.w);
        // 4 consecutive k stay inside one 8-halfword lane slot (col % 4 == 0)
        *(ushort4*)(A + frag_addr(row, col)) = o;
    } else {
        int b  = blk - NPACKA;
        int n0 = (b & 127) * 32;             // column in W  (0..NDIM)
        int k0 = (b >> 7) * 32;              // row in W     (0..KDIM)
        int tx = threadIdx.x & 31, ty = threadIdx.x >> 5;   // 32 x 8
#pragma unroll
        for (int j = 0; j < 4; j++) {
            int k = k0 + ty + 8 * j;
            float v;
            if (k < IDIM) v = Wi[(size_t)k * NDIM + n0 + tx];
            else          v = Wh[(size_t)(k - IDIM) * NDIM + n0 + tx];
            tile[ty + 8 * j][tx] = v;
        }
        __syncthreads();
#pragma unroll
        for (int j = 0; j < 4; j++) {
            int n = n0 + ty + 8 * j;         // Wt row (output col)
            int k = k0 + tx;
            Wt[frag_addr(n, k)] = f2bf(tile[tx][ty + 8 * j]);
        }
    }
}

// ---------------- Kernel 2: bf16 GEMM gates = A @ Wt^T (bf16 out) ----------
// R5: ZERO-LDS register GEMM. R2-R4 showed the LDS pipe over-subscribed
// (frag reads 96KB + staging writes 32KB ~ 1400 cyc/tile > MFMA 1242) and the
// ring's block barrier kept all 8 waves lockstepped -> pipes serialized
// (~2500 cyc/tile at 101-114us across 3 schedule variants).
// Now A and Wt are pre-packed in MFMA-fragment order (1024B blocks, lane*16B)
// so every fragment is ONE perfectly-coalesced global_load_dwordx4 to
// registers. No LDS, no barriers: 8 waves free-run (m114 overlap), operands
// L1/L2-resident (per-tile unique A+B = 32KB; A-slice 3MB/XCD via the XCD
// block mapping). Register ping-pong double-buffer, static indices; the
// compiler's counted-vmcnt insertion keeps 12 loads in flight across the
// MFMA clusters (never drains to 0 until the tail).
// 256x256 block tile, 8 waves (2M x 4N), wave tile 128x64, BK=32.
__global__ __launch_bounds__(512, 2) void gemm_bt(const unsigned short* __restrict__ A,
                                                  const unsigned short* __restrict__ Bt,
                                                  unsigned short* __restrict__ C) {
    const int t    = threadIdx.x;
    const int wave = t >> 6;
    const int lane = t & 63;
    const int lrow = lane & 15;
    const int quad = lane >> 4;
    const int l8   = lane * 8;                     // shorts: lane*16B

    const int bid = blockIdx.x;
    const int xcd = bid & 7;
    const int jj  = bid >> 3;                      // 0..63 within XCD
    const int bm  = (xcd * 4 + (jj & 3)) * 256;    // XCD owns 4 M-panels
    const int bn  = (jj >> 2) * 256;               // 16 N-panels

    const int wm = (wave & 1) * 128;
    const int wn = (wave >> 1) * 64;
    const int m16w = (bm + wm) >> 4;               // fragment-row base (A)
    const int n16w = (bn + wn) >> 4;               // fragment-row base (B)

    f32x4 acc[8][4] = {};

#define LOAD_SET(aa, bb, ktv) {                                                     \
    _Pragma("unroll")                                                               \
    for (int mt = 0; mt < 8; mt++)                                                  \
        aa[mt] = *(const bf16x8*)(A + ((size_t)((m16w + mt) * NKT + (ktv)) << 9) + l8); \
    _Pragma("unroll")                                                               \
    for (int nt = 0; nt < 4; nt++)                                                  \
        bb[nt] = *(const bf16x8*)(Bt + ((size_t)((n16w + nt) * NKT + (ktv)) << 9) + l8); }

#define MFMA_SET(aa, bb) {                                                          \
    _Pragma("unroll")                                                               \
    for (int mt = 0; mt < 8; mt++)                                                  \
        _Pragma("unroll")                                                           \
        for (int nt = 0; nt < 4; nt++)                                              \
            acc[mt][nt] = __builtin_amdgcn_mfma_f32_16x16x32_bf16(                  \
                aa[mt], bb[nt], acc[mt][nt], 0, 0, 0); }

    bf16x8 a0[8], b0[4], a1[8], b1[4];
    LOAD_SET(a0, b0, 0);
    for (int kt = 0; kt < NKT; kt += 2) {
        LOAD_SET(a1, b1, kt + 1);      // prefetch odd tile (12 loads in flight)
        MFMA_SET(a0, b0);              // compiler waits vmcnt(12) here
        if (kt + 2 < NKT) LOAD_SET(a0, b0, kt + 2);
        MFMA_SET(a1, b1);
    }
#undef LOAD_SET
#undef MFMA_SET

#pragma unroll
    for (int mt = 0; mt < 8; mt++)
#pragma unroll
        for (int nt = 0; nt < 4; nt++) {
            int row = bm + wm + mt * 16 + quad * 4;
            int col = bn + wn + nt * 16 + lrow;
#pragma unroll
            for (int r = 0; r < 4; r++)
                C[(size_t)(row + r) * NDIM + col] = f2bf(acc[mt][nt][r]);
        }
}

// ---------------- Kernel 3: per-row LN + LSTM epilogue ---------------------
// One WAVE per batch row (4 rows/block). Lane l owns columns [16l,16l+16) of
// all 4 gates -> the 4 LN reductions are full-wave shuffle reductions and the
// i/f/g/o combine is intra-lane. No LDS, no __syncthreads.
__global__ __launch_bounds__(256) void lstm_ep(const unsigned short* __restrict__ gates,
                                               const float* __restrict__ bh,
                                               const float* __restrict__ c,
                                               const float* __restrict__ gamma,
                                               const float* __restrict__ beta,
                                               float* __restrict__ out) {
    const int wave = threadIdx.x >> 6;
    const int lane = threadIdx.x & 63;
    const int b    = blockIdx.x * 4 + wave;
    const int col0 = lane * 16;

    const unsigned short* gr = gates + (size_t)b * NDIM;
    float v[4][16];
    float s[4], sq[4];
#pragma unroll
    for (int g = 0; g < 4; g++) {
        const unsigned short* gp = gr + g * HDIM + col0;
        u16x8 ga = *(const u16x8*)gp;
        u16x8 gb = *(const u16x8*)(gp + 8);
        float bb[16];
#pragma unroll
        for (int q = 0; q < 4; q++)
            *(float4*)(bb + 4 * q) = ((const float4*)(bh + g * HDIM + col0))[q];
        float ls = 0.f, lq = 0.f;
#pragma unroll
        for (int j = 0; j < 16; j++) {
            float tv = bf2f(j < 8 ? ga[j] : gb[j - 8]) + bb[j];
            v[g][j] = tv; ls += tv; lq += tv * tv;
        }
        s[g] = ls; sq[g] = lq;
    }
#pragma unroll
    for (int off = 32; off; off >>= 1) {
#pragma unroll
        for (int g = 0; g < 4; g++) {
            s[g]  += __shfl_xor(s[g], off);
            sq[g] += __shfl_xor(sq[g], off);
        }
    }
#pragma unroll
    for (int g = 0; g < 4; g++) {
        const float mu  = s[g] * (1.f / HDIM);
        const float var = sq[g] * (1.f / HDIM) - mu * mu;
        const float rs  = rsqrtf(var + 1e-5f);
        float gm[16], bt[16];
#pragma unroll
        for (int q = 0; q < 4; q++) {
            *(float4*)(gm + 4 * q) = ((const float4*)(gamma + g * HDIM + col0))[q];
            *(float4*)(bt + 4 * q) = ((const float4*)(beta  + g * HDIM + col0))[q];
        }
#pragma unroll
        for (int j = 0; j < 16; j++) {
            float y = (v[g][j] - mu) * rs * gm[j] + bt[j];
            v[g][j] = (g == 2) ? ftanh(y) : sigm(y);
        }
    }
    const size_t base = (size_t)b * HDIM + col0;
#pragma unroll
    for (int q = 0; q < 4; q++) {
        float4 ci = *(const float4*)(c + base + 4 * q);
        float4 cn, hn;
#pragma unroll
        for (int e = 0; e < 4; e++) {
            int j = 4 * q + e;
            float cnv = v[1][j] * ((float*)&ci)[e] + v[0][j] * v[2][j];
            ((float*)&cn)[e] = cnv;
            ((float*)&hn)[e] = v[3][j] * ftanh(cnv);
        }
        *(float4*)(out + base + 4 * q) = hn;                               // h_new
        *(float4*)(out + (size_t)BATCH * HDIM + base + 4 * q) = cn;        // c_new
    }
}

extern "C" void kernel_launch(void* const* d_in, const int* in_sizes, int n_in,
                              void* d_out, int out_size, void* d_ws, size_t ws_size,
                              hipStream_t stream) {
    const float* x     = (const float*)d_in[0];
    const float* h     = (const float*)d_in[1];
    const float* c     = (const float*)d_in[2];
    const float* Wi    = (const float*)d_in[3];
    const float* Wh    = (const float*)d_in[4];
    const float* bh    = (const float*)d_in[5];
    const float* gamma = (const float*)d_in[6];
    const float* beta  = (const float*)d_in[7];
    float* out = (float*)d_out;

    // workspace layout
    unsigned short* A  = (unsigned short*)d_ws;                                        // 25.2 MB
    unsigned short* Wt = (unsigned short*)((char*)d_ws + (size_t)BATCH * KDIM * 2);    // 12.6 MB
    unsigned short* gates = (unsigned short*)((char*)d_ws + (size_t)BATCH * KDIM * 2
                                                          + (size_t)NDIM * KDIM * 2); // 64 MB

    pack_ab<<<NPACKA + NPACKW, 256, 0, stream>>>(x, h, Wi, Wh, A, Wt);
    gemm_bt<<<dim3((BATCH / 256) * (NDIM / 256)), 512, 0, stream>>>(A, Wt, gates);
    lstm_ep<<<BATCH / 4, 256, 0, stream>>>(gates, bh, c, gamma, beta, out);
}

// Round 6
// 301.159 us; speedup vs baseline: 1.0781x; 1.0781x over previous
//
#include <hip/hip_runtime.h>
#include <stdint.h>

// Problem constants (fixed by setup_inputs): B=8192, I=512, H=1024
#define BATCH 8192
#define IDIM  512
#define HDIM  1024
#define KDIM  1536          // I + H
#define NDIM  4096          // 4*H
#define BK    32

typedef __bf16 bf16x8 __attribute__((ext_vector_type(8)));
typedef float  f32x4  __attribute__((ext_vector_type(4)));
typedef unsigned short u16x8 __attribute__((ext_vector_type(8)));

__device__ __forceinline__ unsigned short f2bf(float f) {
    union { float f; unsigned u; } v; v.f = f;
    unsigned r = v.u + 0x7fffu + ((v.u >> 16) & 1u);   // RNE
    return (unsigned short)(r >> 16);
}
__device__ __forceinline__ float bf2f(unsigned short u) {
    union { unsigned u; float f; } v; v.u = ((unsigned)u) << 16;
    return v.f;
}
__device__ __forceinline__ float fexp(float x) {      // e^x via v_exp_f32
    return __builtin_amdgcn_exp2f(x * 1.44269504f);
}
__device__ __forceinline__ float sigm(float x) {      // stable for |x| large
    return __builtin_amdgcn_rcpf(1.f + fexp(-x));
}
__device__ __forceinline__ float ftanh(float x) {     // 1 - 2/(e^{2x}+1)
    return 1.f - 2.f * __builtin_amdgcn_rcpf(1.f + fexp(2.f * x));
}

__device__ __forceinline__ void load16(void* lds, const void* g) {
    __builtin_amdgcn_global_load_lds(
        (const __attribute__((address_space(1))) unsigned int*)g,
        (__attribute__((address_space(3))) unsigned int*)lds, 16, 0, 0);
}

// ------------- Kernel 1: fused input packing (R6: fat blocks) -------------
// blocks [0, PACKA_BLKS): pack [x|h] -> bf16 A (BATCH x KDIM) row-major.
//   1 ushort8 (16B) store per thread from 2x float4 reads.
// blocks [PACKA_BLKS, ..): transpose+convert [Wi;Wh] -> bf16 Wt
//   (NDIM x KDIM) row-major. 64n x 32k tile per block; writes are ushort4
//   (8B) -> 64B contiguous segments per 8 lanes (was 2B scalar stores).
#define PACKA_BLKS (BATCH * KDIM / 8 / 512)             // 3072
#define PACKW_BLKS ((NDIM / 64) * (KDIM / 32))          // 3072
__global__ __launch_bounds__(512) void pack_ab(const float* __restrict__ x,
                                               const float* __restrict__ h,
                                               const float* __restrict__ Wi,
                                               const float* __restrict__ Wh,
                                               unsigned short* __restrict__ A,
                                               unsigned short* __restrict__ Wt) {
    __shared__ float tile[32][65];
    const int t   = threadIdx.x;
    const int blk = blockIdx.x;
    if (blk < PACKA_BLKS) {
        int idx = blk * 512 + t;             // ushort8 group
        int row = idx / (KDIM / 8);
        int g8  = idx % (KDIM / 8);          // 0..191
        const float* src = (g8 < IDIM / 8)
                         ? x + (size_t)row * IDIM + g8 * 8
                         : h + (size_t)row * HDIM + (g8 - IDIM / 8) * 8;
        float4 v0 = ((const float4*)src)[0];
        float4 v1 = ((const float4*)src)[1];
        u16x8 o;
        o[0] = f2bf(v0.x); o[1] = f2bf(v0.y); o[2] = f2bf(v0.z); o[3] = f2bf(v0.w);
        o[4] = f2bf(v1.x); o[5] = f2bf(v1.y); o[6] = f2bf(v1.z); o[7] = f2bf(v1.w);
        *(u16x8*)(A + (size_t)idx * 8) = o;
    } else {
        int b  = blk - PACKA_BLKS;
        int n0 = (b & 63) * 64;              // 64 n-blocks
        int k0 = (b >> 6) * 32;              // 48 k-blocks
        int tx = t & 63, ty = t >> 6;        // 64 x 8
#pragma unroll
        for (int j = 0; j < 4; j++) {
            int k = k0 + ty + 8 * j;
            float v;
            if (k < IDIM) v = Wi[(size_t)k * NDIM + n0 + tx];
            else          v = Wh[(size_t)(k - IDIM) * NDIM + n0 + tx];
            tile[ty + 8 * j][tx] = v;
        }
        __syncthreads();
        int nl = t >> 3, k4 = (t & 7) * 4;   // 64 n-rows x 8 k-quads
        ushort4 o;
        o.x = f2bf(tile[k4 + 0][nl]);
        o.y = f2bf(tile[k4 + 1][nl]);
        o.z = f2bf(tile[k4 + 2][nl]);
        o.w = f2bf(tile[k4 + 3][nl]);
        *(ushort4*)(Wt + (size_t)(n0 + nl) * KDIM + k0 + k4) = o;
    }
}

// ---------------- Kernel 2: bf16 GEMM gates = A @ Wt^T (bf16 out) ----------
// R2 configuration verbatim (best measured: 101us, MfmaUtil 45%).
// 256x256 tile, BK=32, 8 waves (2M x 4N), 4-slot LDS ring (128 KB), counted
// vmcnt(8) handoff, coarse-pinned read->stage->MFMA order per tile.
__global__ __launch_bounds__(512, 2) void gemm_bt(const unsigned short* __restrict__ A,
                                                  const unsigned short* __restrict__ Bt,
                                                  unsigned short* __restrict__ C) {
    __shared__ __align__(16) unsigned short smem[65536];   // 128 KB: 4 x (A 16KB | B 16KB)

    const int t    = threadIdx.x;
    const int wave = t >> 6;
    const int lane = t & 63;
    const int lrow = lane & 15;
    const int quad = lane >> 4;

    const int bid = blockIdx.x;
    const int xcd = bid & 7;
    const int jj  = bid >> 3;                      // 0..63 within XCD
    const int bm  = (xcd * 4 + (jj & 3)) * 256;    // XCD owns 4 M-panels
    const int bn  = (jj >> 2) * 256;               // 16 N-panels

    const int wm = (wave & 1) * 128;
    const int wn = (wave >> 1) * 64;

    // stage source offsets (shorts): bank swizzle folded into global src addr
    int srcA[2], srcB[2];
#pragma unroll
    for (int j = 0; j < 2; j++) {
        int q   = t + 512 * j;
        int rp  = q >> 3, s = q & 7;
        int xx  = s ^ (rp & 7);
        int row = 2 * rp + (xx >> 2);
        int kc  = xx & 3;
        srcA[j] = (bm + row) * KDIM + kc * 8;
        srcB[j] = (bn + row) * KDIM + kc * 8;
    }

    // ds_read fragment offsets (shorts), constant across tiles
    int offA[8], offB[4];
#pragma unroll
    for (int mt = 0; mt < 8; mt++) {
        int r = wm + mt * 16 + lrow;
        offA[mt] = (r >> 1) * 64 + (((((r & 1) << 2) | quad) ^ ((r >> 1) & 7)) * 8);
    }
#pragma unroll
    for (int nt = 0; nt < 4; nt++) {
        int r = wn + nt * 16 + lrow;
        offB[nt] = (r >> 1) * 64 + (((((r & 1) << 2) | quad) ^ ((r >> 1) & 7)) * 8);
    }

    f32x4 acc[8][4] = {};

#define STAGE(tt) do {                                              \
    unsigned short* _d = smem + (((tt) & 3) << 14);                 \
    const int _ko = (tt) * 32;                                      \
    load16(_d +          t * 8, A  + (size_t)(srcA[0] + _ko));      \
    load16(_d +  4096 +  t * 8, A  + (size_t)(srcA[1] + _ko));      \
    load16(_d +  8192 +  t * 8, Bt + (size_t)(srcB[0] + _ko));      \
    load16(_d + 12288 +  t * 8, Bt + (size_t)(srcB[1] + _ko));      \
} while (0)

    STAGE(0); STAGE(1); STAGE(2);

    const int NT = KDIM / 32;          // 48
    for (int T = 0; T < NT; ++T) {
        // handoff: tile T's 4 staging loads (per thread) must be done; keep
        // tiles T+1,T+2 (8 loads) in flight. Drain 8->4->0 only at the tail.
        if (T < NT - 2)       asm volatile("s_waitcnt vmcnt(8)" ::: "memory");
        else if (T == NT - 2) asm volatile("s_waitcnt vmcnt(4)" ::: "memory");
        else                  asm volatile("s_waitcnt vmcnt(0)" ::: "memory");
        __builtin_amdgcn_s_barrier();
        asm volatile("" ::: "memory");   // fence: no LDS reads hoist above

        const unsigned short* bufA = smem + ((T & 3) << 14);
        const unsigned short* bufB = bufA + 8192;

        // ---- issue ALL fragment reads up front (12 x ds_read_b128) -------
        bf16x8 a[4], b[4], a2[4];
#pragma unroll
        for (int i = 0; i < 4; i++) a[i] = *(const bf16x8*)(bufA + offA[i]);
#pragma unroll
        for (int i = 0; i < 4; i++) b[i] = *(const bf16x8*)(bufB + offB[i]);
        __builtin_amdgcn_sched_barrier(0);   // a,b group issues first
        if (T + 3 < NT) STAGE(T + 3);        // slot (T-1)&3: freed by barrier
#pragma unroll
        for (int i = 0; i < 4; i++) a2[i] = *(const bf16x8*)(bufA + offA[4 + i]);
        __builtin_amdgcn_sched_barrier(0);   // all reads pinned above MFMAs

        // ---- MFMA cluster 0: waits lgkmcnt(4) (a2 still in flight) -------
        __builtin_amdgcn_s_setprio(1);
#pragma unroll
        for (int mt = 0; mt < 4; mt++)
#pragma unroll
            for (int nt = 0; nt < 4; nt++)
                acc[mt][nt] = __builtin_amdgcn_mfma_f32_16x16x32_bf16(
                    a[mt], b[nt], acc[mt][nt], 0, 0, 0);
        __builtin_amdgcn_sched_barrier(0);   // keep cluster 1 after cluster 0

        // ---- MFMA cluster 1: waits lgkmcnt(0) for a2 ---------------------
#pragma unroll
        for (int mt = 0; mt < 4; mt++)
#pragma unroll
            for (int nt = 0; nt < 4; nt++)
                acc[4 + mt][nt] = __builtin_amdgcn_mfma_f32_16x16x32_bf16(
                    a2[mt], b[nt], acc[4 + mt][nt], 0, 0, 0);
        __builtin_amdgcn_s_setprio(0);
        asm volatile("" ::: "memory");       // reads stay inside this tile
    }
#undef STAGE

#pragma unroll
    for (int mt = 0; mt < 8; mt++)
#pragma unroll
        for (int nt = 0; nt < 4; nt++) {
            int row = bm + wm + mt * 16 + quad * 4;
            int col = bn + wn + nt * 16 + lrow;
#pragma unroll
            for (int r = 0; r < 4; r++)
                C[(size_t)(row + r) * NDIM + col] = f2bf(acc[mt][nt][r]);
        }
}

// ---------------- Kernel 3: per-row LN + LSTM epilogue ---------------------
// R6: 512-thread blocks (8 rows/block, one WAVE per row), 1024 blocks.
// Lane l owns columns [16l,16l+16) of all 4 gates -> the 4 LN reductions are
// full-wave shuffle reductions and the i/f/g/o combine is intra-lane.
__global__ __launch_bounds__(512) void lstm_ep(const unsigned short* __restrict__ gates,
                                               const float* __restrict__ bh,
                                               const float* __restrict__ c,
                                               const float* __restrict__ gamma,
                                               const float* __restrict__ beta,
                                               float* __restrict__ out) {
    const int wave = threadIdx.x >> 6;
    const int lane = threadIdx.x & 63;
    const int b    = blockIdx.x * 8 + wave;
    const int col0 = lane * 16;

    const unsigned short* gr = gates + (size_t)b * NDIM;
    float v[4][16];
    float s[4], sq[4];
#pragma unroll
    for (int g = 0; g < 4; g++) {
        const unsigned short* gp = gr + g * HDIM + col0;
        u16x8 ga = *(const u16x8*)gp;
        u16x8 gb = *(const u16x8*)(gp + 8);
        float bb[16];
#pragma unroll
        for (int q = 0; q < 4; q++)
            *(float4*)(bb + 4 * q) = ((const float4*)(bh + g * HDIM + col0))[q];
        float ls = 0.f, lq = 0.f;
#pragma unroll
        for (int j = 0; j < 16; j++) {
            float tv = bf2f(j < 8 ? ga[j] : gb[j - 8]) + bb[j];
            v[g][j] = tv; ls += tv; lq += tv * tv;
        }
        s[g] = ls; sq[g] = lq;
    }
#pragma unroll
    for (int off = 32; off; off >>= 1) {
#pragma unroll
        for (int g = 0; g < 4; g++) {
            s[g]  += __shfl_xor(s[g], off);
            sq[g] += __shfl_xor(sq[g], off);
        }
    }
#pragma unroll
    for (int g = 0; g < 4; g++) {
        const float mu  = s[g] * (1.f / HDIM);
        const float var = sq[g] * (1.f / HDIM) - mu * mu;
        const float rs  = rsqrtf(var + 1e-5f);
        float gm[16], bt[16];
#pragma unroll
        for (int q = 0; q < 4; q++) {
            *(float4*)(gm + 4 * q) = ((const float4*)(gamma + g * HDIM + col0))[q];
            *(float4*)(bt + 4 * q) = ((const float4*)(beta  + g * HDIM + col0))[q];
        }
#pragma unroll
        for (int j = 0; j < 16; j++) {
            float y = (v[g][j] - mu) * rs * gm[j] + bt[j];
            v[g][j] = (g == 2) ? ftanh(y) : sigm(y);
        }
    }
    const size_t base = (size_t)b * HDIM + col0;
#pragma unroll
    for (int q = 0; q < 4; q++) {
        float4 ci = *(const float4*)(c + base + 4 * q);
        float4 cn, hn;
#pragma unroll
        for (int e = 0; e < 4; e++) {
            int j = 4 * q + e;
            float cnv = v[1][j] * ((float*)&ci)[e] + v[0][j] * v[2][j];
            ((float*)&cn)[e] = cnv;
            ((float*)&hn)[e] = v[3][j] * ftanh(cnv);
        }
        *(float4*)(out + base + 4 * q) = hn;                               // h_new
        *(float4*)(out + (size_t)BATCH * HDIM + base + 4 * q) = cn;        // c_new
    }
}

extern "C" void kernel_launch(void* const* d_in, const int* in_sizes, int n_in,
                              void* d_out, int out_size, void* d_ws, size_t ws_size,
                              hipStream_t stream) {
    const float* x     = (const float*)d_in[0];
    const float* h     = (const float*)d_in[1];
    const float* c     = (const float*)d_in[2];
    const float* Wi    = (const float*)d_in[3];
    const float* Wh    = (const float*)d_in[4];
    const float* bh    = (const float*)d_in[5];
    const float* gamma = (const float*)d_in[6];
    const float* beta  = (const float*)d_in[7];
    float* out = (float*)d_out;

    // workspace layout
    unsigned short* A  = (unsigned short*)d_ws;                                        // 25.2 MB
    unsigned short* Wt = (unsigned short*)((char*)d_ws + (size_t)BATCH * KDIM * 2);    // 12.6 MB
    unsigned short* gates = (unsigned short*)((char*)d_ws + (size_t)BATCH * KDIM * 2
                                                          + (size_t)NDIM * KDIM * 2); // 64 MB

    pack_ab<<<PACKA_BLKS + PACKW_BLKS, 512, 0, stream>>>(x, h, Wi, Wh, A, Wt);
    gemm_bt<<<dim3((BATCH / 256) * (NDIM / 256)), 512, 0, stream>>>(A, Wt, gates);
    lstm_ep<<<BATCH / 8, 512, 0, stream>>>(gates, bh, c, gamma, beta, out);
}